// Round 1
// baseline (282.952 us; speedup 1.0000x reference)
//
#include <hip/hip_runtime.h>

// Tensor-network binary tree contraction, fp32 (precision requires fp32:
// relative error amplifies ~2x per level; bf16 would blow the 2% threshold).
//
// Mapping: 4 threads per sample (one per quarter-subtree of 64 features).
// Block = 256 threads = 4 waves; wave q handles quarter q of 64 samples
// (sample = blockIdx.x*64 + lane). Weight addresses are wave-uniform
// (q via readfirstlane) -> scalar loads. Depth-first traversal keeps one
// pending buffer per level in registers (all statically indexed).

__device__ __forceinline__ void combine8(const float* __restrict__ w,
                                         const float L[8], const float R[8],
                                         float out[8]) {
    float acc[8];
#pragma unroll
    for (int k = 0; k < 8; ++k) acc[k] = 0.f;
#pragma unroll
    for (int i = 0; i < 8; ++i) {
#pragma unroll
        for (int j = 0; j < 8; ++j) {
            const float o = L[i] * R[j];
            const float* wp = w + (i * 8 + j) * 8;
#pragma unroll
            for (int k = 0; k < 8; ++k) acc[k] = fmaf(o, wp[k], acc[k]);
        }
    }
#pragma unroll
    for (int k = 0; k < 8; ++k) out[k] = acc[k];
}

__device__ __forceinline__ void copy8(float dst[8], const float src[8]) {
#pragma unroll
    for (int k = 0; k < 8; ++k) dst[k] = src[k];
}

__global__ __launch_bounds__(256, 4)
void tn_tree_kernel(const float* __restrict__ x,
                    const float* __restrict__ w7,
                    const float* __restrict__ w6,
                    const float* __restrict__ w5,
                    const float* __restrict__ w4,
                    const float* __restrict__ w3,
                    const float* __restrict__ w2,
                    const float* __restrict__ w1,
                    const float* __restrict__ w0,
                    float* __restrict__ out) {
    const int lane = threadIdx.x & 63;
    const int q = __builtin_amdgcn_readfirstlane((int)(threadIdx.x >> 6)); // quarter, wave-uniform
    const int b = blockIdx.x * 64 + lane;                                  // sample

    // x[b, f, p] flat = b*512 + f*2 + p. Leaf node n uses features 2n,2n+1
    // -> 4 consecutive floats at b*512 + 4n. This thread's leaves: n = 32q+m.
    const float* xp = x + (size_t)b * 512 + (size_t)q * 128;

    float p7[4], p6[8], p5[8], p4[8], p3[8], res[8];

#pragma unroll 2
    for (int m = 0; m < 32; ++m) {
        // ---- leaf: v4[k] = sum_{i,j<2} x[2n,i] x[2n+1,j] w7[n,i,j,k]
        const float4 xv = *reinterpret_cast<const float4*>(xp + m * 4);
        float v4[4];
        {
            const float* w = w7 + (size_t)(32 * q + m) * 16;
            const float o00 = xv.x * xv.z, o01 = xv.x * xv.w;
            const float o10 = xv.y * xv.z, o11 = xv.y * xv.w;
#pragma unroll
            for (int k = 0; k < 4; ++k)
                v4[k] = fmaf(o00, w[k],
                        fmaf(o01, w[4 + k],
                        fmaf(o10, w[8 + k], o11 * w[12 + k])));
        }
        if ((m & 1) == 0) {
#pragma unroll
            for (int k = 0; k < 4; ++k) p7[k] = v4[k];
            continue;
        }

        // ---- w6: 4x4 -> 8
        float v8[8];
        {
            const float* w = w6 + (size_t)(16 * q + (m >> 1)) * 128;
#pragma unroll
            for (int k = 0; k < 8; ++k) v8[k] = 0.f;
#pragma unroll
            for (int i = 0; i < 4; ++i) {
#pragma unroll
                for (int j = 0; j < 4; ++j) {
                    const float o = p7[i] * v4[j];
                    const float* wp = w + (i * 4 + j) * 8;
#pragma unroll
                    for (int k = 0; k < 8; ++k) v8[k] = fmaf(o, wp[k], v8[k]);
                }
            }
        }
        if ((m & 2) == 0) { copy8(p6, v8); continue; }

        // ---- w5
        float t[8];
        combine8(w5 + (size_t)(8 * q + (m >> 2)) * 512, p6, v8, t);
        if ((m & 4) == 0) { copy8(p5, t); continue; }

        // ---- w4
        combine8(w4 + (size_t)(4 * q + (m >> 3)) * 512, p5, t, v8);
        if ((m & 8) == 0) { copy8(p4, v8); continue; }

        // ---- w3
        combine8(w3 + (size_t)(2 * q + (m >> 4)) * 512, p4, v8, t);
        if ((m & 16) == 0) { copy8(p3, t); continue; }

        // ---- w2 (finishes this quarter)
        combine8(w2 + (size_t)q * 512, p3, t, res);
    }

    // ---- cross-quarter combine via LDS (padded to 9 to spread banks)
    __shared__ float lds[256][9];
    const int slot = q * 64 + lane;
#pragma unroll
    for (int k = 0; k < 8; ++k) lds[slot][k] = res[k];
    __syncthreads();

    if (q < 2) {
        // w1 node q: L = quarter 2q, R = quarter 2q+1
        float L[8], R[8], v1[8];
#pragma unroll
        for (int k = 0; k < 8; ++k) {
            L[k] = lds[2 * q * 64 + lane][k];
            R[k] = lds[(2 * q + 1) * 64 + lane][k];
        }
        combine8(w1 + (size_t)q * 512, L, R, v1);
#pragma unroll
        for (int k = 0; k < 8; ++k) lds[slot][k] = v1[k];
    }
    __syncthreads();

    if (q == 0) {
        float L[8], R[8];
#pragma unroll
        for (int k = 0; k < 8; ++k) {
            L[k] = lds[lane][k];
            R[k] = lds[64 + lane][k];
        }
        float o0 = 0.f, o1 = 0.f;
#pragma unroll
        for (int i = 0; i < 8; ++i) {
#pragma unroll
            for (int j = 0; j < 8; ++j) {
                const float o = L[i] * R[j];
                o0 = fmaf(o, w0[i * 16 + j * 2 + 0], o0);
                o1 = fmaf(o, w0[i * 16 + j * 2 + 1], o1);
            }
        }
        float2 r;
        r.x = o0;
        r.y = o1;
        *reinterpret_cast<float2*>(out + (size_t)b * 2) = r;
    }
}

extern "C" void kernel_launch(void* const* d_in, const int* in_sizes, int n_in,
                              void* d_out, int out_size, void* d_ws, size_t ws_size,
                              hipStream_t stream) {
    const float* x  = (const float*)d_in[0];
    const float* w7 = (const float*)d_in[1];
    const float* w6 = (const float*)d_in[2];
    const float* w5 = (const float*)d_in[3];
    const float* w4 = (const float*)d_in[4];
    const float* w3 = (const float*)d_in[5];
    const float* w2 = (const float*)d_in[6];
    const float* w1 = (const float*)d_in[7];
    const float* w0 = (const float*)d_in[8];
    float* out = (float*)d_out;

    // 65536 samples, 64 samples per block (4 waves: one quarter-subtree each)
    dim3 grid(65536 / 64);
    dim3 block(256);
    hipLaunchKernelGGL(tn_tree_kernel, grid, block, 0, stream,
                       x, w7, w6, w5, w4, w3, w2, w1, w0, out);
}

// Round 3
// 264.841 us; speedup vs baseline: 1.0684x; 1.0684x over previous
//
#include <hip/hip_runtime.h>

// Tensor-network binary tree contraction, fp32 (precision requires fp32:
// relative error amplifies ~2x per level; bf16 would blow the 2% threshold).
//
// Round 3 = round 2 with the depth-first plumbing bug fixed: at m==15 the
// w4 combine writes v8, and the final w3 combine must consume v8 (round 2
// erroneously passed t, the w5-level output).
//
// Mapping: 8 threads per sample (one per EIGHTH-subtree of 32 features).
// Block = 512 threads = 8 waves; wave e handles eighth e of 64 samples
// (sample = blockIdx.x*64 + lane). Grid = 1024 blocks -> 8192 waves =
// 32 waves/CU (max occupancy) to hide the scalar weight-stream latency
// that capped round 1 at VALUBusy=34%. Weight addresses are wave-uniform
// (e via readfirstlane) -> scalar s_loads. Depth-first traversal keeps one
// pending buffer per level in registers (statically indexed).

__device__ __forceinline__ void combine8(const float* __restrict__ w,
                                         const float L[8], const float R[8],
                                         float out[8]) {
    float acc[8];
#pragma unroll
    for (int k = 0; k < 8; ++k) acc[k] = 0.f;
#pragma unroll
    for (int i = 0; i < 8; ++i) {
#pragma unroll
        for (int j = 0; j < 8; ++j) {
            const float o = L[i] * R[j];
            const float* wp = w + (i * 8 + j) * 8;
#pragma unroll
            for (int k = 0; k < 8; ++k) acc[k] = fmaf(o, wp[k], acc[k]);
        }
    }
#pragma unroll
    for (int k = 0; k < 8; ++k) out[k] = acc[k];
}

__device__ __forceinline__ void copy8(float dst[8], const float src[8]) {
#pragma unroll
    for (int k = 0; k < 8; ++k) dst[k] = src[k];
}

__global__ __launch_bounds__(512, 8)
void tn_tree_kernel(const float* __restrict__ x,
                    const float* __restrict__ w7,
                    const float* __restrict__ w6,
                    const float* __restrict__ w5,
                    const float* __restrict__ w4,
                    const float* __restrict__ w3,
                    const float* __restrict__ w2,
                    const float* __restrict__ w1,
                    const float* __restrict__ w0,
                    float* __restrict__ out) {
    const int lane = threadIdx.x & 63;
    const int e = __builtin_amdgcn_readfirstlane((int)(threadIdx.x >> 6)); // eighth, wave-uniform
    const int b = blockIdx.x * 64 + lane;                                  // sample

    // x[b, f, p] flat = b*512 + f*2 + p. Leaf node n uses features 2n,2n+1
    // -> 4 consecutive floats at b*512 + 4n. This wave's leaves: n = 16e+m.
    const float* xp = x + (size_t)b * 512 + (size_t)e * 64;

    float p7[4], p6[8], p5[8], p4[8], res[8];

#pragma unroll 2
    for (int m = 0; m < 16; ++m) {
        // ---- leaf: v4[k] = sum_{i,j<2} x[2n,i] x[2n+1,j] w7[n,i,j,k]
        const float4 xv = *reinterpret_cast<const float4*>(xp + m * 4);
        float v4[4];
        {
            const float* w = w7 + (size_t)(16 * e + m) * 16;
            const float o00 = xv.x * xv.z, o01 = xv.x * xv.w;
            const float o10 = xv.y * xv.z, o11 = xv.y * xv.w;
#pragma unroll
            for (int k = 0; k < 4; ++k)
                v4[k] = fmaf(o00, w[k],
                        fmaf(o01, w[4 + k],
                        fmaf(o10, w[8 + k], o11 * w[12 + k])));
        }
        if ((m & 1) == 0) {
#pragma unroll
            for (int k = 0; k < 4; ++k) p7[k] = v4[k];
            continue;
        }

        // ---- w6: 4x4 -> 8
        float v8[8];
        {
            const float* w = w6 + (size_t)(8 * e + (m >> 1)) * 128;
#pragma unroll
            for (int k = 0; k < 8; ++k) v8[k] = 0.f;
#pragma unroll
            for (int i = 0; i < 4; ++i) {
#pragma unroll
                for (int j = 0; j < 4; ++j) {
                    const float o = p7[i] * v4[j];
                    const float* wp = w + (i * 4 + j) * 8;
#pragma unroll
                    for (int k = 0; k < 8; ++k) v8[k] = fmaf(o, wp[k], v8[k]);
                }
            }
        }
        if ((m & 2) == 0) { copy8(p6, v8); continue; }

        // ---- w5
        float t[8];
        combine8(w5 + (size_t)(4 * e + (m >> 2)) * 512, p6, v8, t);
        if ((m & 4) == 0) { copy8(p5, t); continue; }

        // ---- w4
        combine8(w4 + (size_t)(2 * e + (m >> 3)) * 512, p5, t, v8);
        if ((m & 8) == 0) { copy8(p4, v8); continue; }

        // ---- w3 (finishes this eighth; consumes w4's output v8)
        combine8(w3 + (size_t)e * 512, p4, v8, res);
    }

    // ---- cross-eighth combine via LDS (padded to 9 to spread banks)
    __shared__ float lds[512][9];
    const int slot = e * 64 + lane;
#pragma unroll
    for (int k = 0; k < 8; ++k) lds[slot][k] = res[k];
    __syncthreads();

    if (e < 4) {
        // w2 node e: L = eighth 2e, R = eighth 2e+1
        float L[8], R[8], v2[8];
#pragma unroll
        for (int k = 0; k < 8; ++k) {
            L[k] = lds[2 * e * 64 + lane][k];
            R[k] = lds[(2 * e + 1) * 64 + lane][k];
        }
        combine8(w2 + (size_t)e * 512, L, R, v2);
#pragma unroll
        for (int k = 0; k < 8; ++k) lds[slot][k] = v2[k];
    }
    __syncthreads();

    if (e < 2) {
        // w1 node e: L = w2-result 2e, R = w2-result 2e+1
        float L[8], R[8], v1[8];
#pragma unroll
        for (int k = 0; k < 8; ++k) {
            L[k] = lds[2 * e * 64 + lane][k];
            R[k] = lds[(2 * e + 1) * 64 + lane][k];
        }
        combine8(w1 + (size_t)e * 512, L, R, v1);
#pragma unroll
        for (int k = 0; k < 8; ++k) lds[slot][k] = v1[k];
    }
    __syncthreads();

    if (e == 0) {
        float L[8], R[8];
#pragma unroll
        for (int k = 0; k < 8; ++k) {
            L[k] = lds[lane][k];
            R[k] = lds[64 + lane][k];
        }
        float o0 = 0.f, o1 = 0.f;
#pragma unroll
        for (int i = 0; i < 8; ++i) {
#pragma unroll
            for (int j = 0; j < 8; ++j) {
                const float o = L[i] * R[j];
                o0 = fmaf(o, w0[i * 16 + j * 2 + 0], o0);
                o1 = fmaf(o, w0[i * 16 + j * 2 + 1], o1);
            }
        }
        float2 r;
        r.x = o0;
        r.y = o1;
        *reinterpret_cast<float2*>(out + (size_t)b * 2) = r;
    }
}

extern "C" void kernel_launch(void* const* d_in, const int* in_sizes, int n_in,
                              void* d_out, int out_size, void* d_ws, size_t ws_size,
                              hipStream_t stream) {
    const float* x  = (const float*)d_in[0];
    const float* w7 = (const float*)d_in[1];
    const float* w6 = (const float*)d_in[2];
    const float* w5 = (const float*)d_in[3];
    const float* w4 = (const float*)d_in[4];
    const float* w3 = (const float*)d_in[5];
    const float* w2 = (const float*)d_in[6];
    const float* w1 = (const float*)d_in[7];
    const float* w0 = (const float*)d_in[8];
    float* out = (float*)d_out;

    // 65536 samples, 64 samples per block (8 waves: one eighth-subtree each)
    dim3 grid(65536 / 64);
    dim3 block(512);
    hipLaunchKernelGGL(tn_tree_kernel, grid, block, 0, stream,
                       x, w7, w6, w5, w4, w3, w2, w1, w0, out);
}